// Round 20
// baseline (368.181 us; speedup 1.0000x reference)
//
#include <hip/hip_runtime.h>
#include <cstdint>

#define NB   2
#define TSEQ 2048
#define NT   4096
#define CDIM 1024
#define DDIM 128
#define FFDIM 2048
#define NE   8
#define ABCAP 8192
#define NTIL 40

#define MB(x) ((size_t)(x) << 20)

#define OFF_CA   ((size_t)0)
#define OFF_CM   ((size_t)64)
#define OFF_CI   ((size_t)128)
#define OFF_PA   ((size_t)256)
#define OFF_PM   ((size_t)320)
#define OFF_WA   ((size_t)1024)
#define OFF_WM   (OFF_WA + (size_t)NT*NE*4)
#define OFF_LA   (OFF_WM + (size_t)NT*NE*4)
#define OFF_LM   (OFF_LA + (size_t)NT*NE*4)
#define OFF_RTA  ((size_t)600*1024)
#define OFF_RTM  ((size_t)632*1024)
#define OFF_MBA  ((size_t)664*1024)
#define OFF_MBM  ((size_t)680*1024)
#define OFF_QB   MB(1)
#define OFF_KB   MB(3)
#define OFF_VB   MB(5)
#define OFF_AO   MB(7)
#define OFF_QHI  MB(9)
#define OFF_QLO  MB(10)
#define OFF_KHI  MB(11)
#define OFF_KLO  MB(12)
#define OFF_VTH  MB(13)
#define OFF_VTL  MB(14)
#define OFF_ML   MB(15)
#define OFF_WQKVT MB(16)
#define OFF_WOT  MB(22)
#define OFF_APOP MB(24)
#define OFF_APQKV MB(26)
#define OFF_OP   MB(26)
#define OFF_APM  MB(59)
#define OFF_W1T  MB(75)
#define OFF_AB2  MB(107)

typedef __attribute__((ext_vector_type(8))) short bf16x8;
typedef __attribute__((ext_vector_type(4))) float f32x4;

#define SW(r) (((r) >> 1) & 3)

__device__ __forceinline__ float gelu_tanh(float x) {
    float x3 = x*x*x;
    float z2 = 1.5957691216057308f*(x + 0.044715f*x3);
    float t = 1.0f - 2.0f/(__expf(z2) + 1.0f);
    return 0.5f*x*(1.0f + t);
}

__device__ __forceinline__ unsigned short f2bf(float f) {
    union { float f; uint32_t u; } v; v.f = f;
    uint32_t r = (v.u + 0x7fff + ((v.u >> 16) & 1)) >> 16;
    return (unsigned short)r;
}
__device__ __forceinline__ float bf2f(unsigned short h) {
    union { uint32_t u; float f; } v; v.u = ((uint32_t)h) << 16; return v.f;
}

__device__ __forceinline__ void gload16(const unsigned short* g, unsigned short* l) {
    __builtin_amdgcn_global_load_lds(
        (const __attribute__((address_space(1))) void*)g,
        (__attribute__((address_space(3))) void*)l,
        16, 0, 0);
}

__global__ void colnorm_kernel(const float* __restrict__ asim,
                               const float* __restrict__ msim,
                               float* __restrict__ inv) {
    int col = blockIdx.x;
    const float* s = (col < NE) ? asim : msim;
    int e = col & (NE-1);
    int tid = threadIdx.x;
    float ss = 0.0f;
    for (int c = tid; c < CDIM; c += 256) { float v = s[(size_t)c*NE + e]; ss += v*v; }
    __shared__ float red[256];
    red[tid] = ss; __syncthreads();
    for (int st = 128; st > 0; st >>= 1) { if (tid < st) red[tid] += red[tid+st]; __syncthreads(); }
    if (tid == 0) inv[col] = 1.0f / fmaxf(sqrtf(red[0]), 1e-12f);
}

__global__ void gating_kernel(const float* __restrict__ xin,
                              const float* __restrict__ sim,
                              const float* __restrict__ gates,
                              const float* __restrict__ colinv,
                              const int* __restrict__ kmin_p,
                              float* __restrict__ wout,
                              unsigned int* __restrict__ mbits) {
    const int n = blockIdx.x, tid = threadIdx.x;
    const float* xr = xin + (size_t)n*CDIM;
    float4 xv = *(const float4*)(xr + tid*4);
    float acc[9];
    acc[0] = xv.x*xv.x + xv.y*xv.y + xv.z*xv.z + xv.w*xv.w;
    int c = tid*4;
    #pragma unroll
    for (int e = 0; e < NE; e++)
        acc[1+e] = xv.x*sim[(size_t)(c+0)*NE+e] + xv.y*sim[(size_t)(c+1)*NE+e]
                 + xv.z*sim[(size_t)(c+2)*NE+e] + xv.w*sim[(size_t)(c+3)*NE+e];
    __shared__ float red[9][256];
    #pragma unroll
    for (int a = 0; a < 9; a++) red[a][tid] = acc[a];
    __syncthreads();
    for (int s = 128; s > 0; s >>= 1) {
        if (tid < s) {
            #pragma unroll
            for (int a = 0; a < 9; a++) red[a][tid] += red[a][tid+s];
        }
        __syncthreads();
    }
    if (tid == 0) {
        float xinv = 1.0f / fmaxf(sqrtf(red[0][0]), 1e-12f);
        float logits[NE], gated[NE];
        int mask[NE]; int any = 0;
        #pragma unroll
        for (int e = 0; e < NE; e++) {
            float lg = red[1+e][0]*xinv*colinv[e] - 1.0f/(1.0f + expf(-gates[e]));
            logits[e] = lg; gated[e] = fmaxf(lg, 0.0f);
            mask[e] = (lg > 0.0f) ? 1 : 0; any |= mask[e];
        }
        if (!any) {
            int kmin = *kmin_p; if (kmin < 1) kmin = 1; if (kmin > NE) kmin = NE;
            int used[NE] = {0,0,0,0,0,0,0,0};
            for (int kk = 0; kk < kmin; kk++) {
                int best = -1; float bv = 0.0f;
                for (int e = 0; e < NE; e++)
                    if (!used[e] && (best < 0 || logits[e] > bv)) { best = e; bv = logits[e]; }
                used[best] = 1; mask[best] = 1;
            }
        }
        float mx = -3.402823466e38f;
        #pragma unroll
        for (int e = 0; e < NE; e++) { float me = mask[e] ? gated[e] : -1.0e9f; mx = fmaxf(mx, me); }
        float sum = 0.0f, p[NE];
        #pragma unroll
        for (int e = 0; e < NE; e++) { p[e] = expf((mask[e] ? gated[e] : -1.0e9f) - mx); sum += p[e]; }
        float sinv = 1.0f / sum;
        unsigned int bits = 0;
        #pragma unroll
        for (int e = 0; e < NE; e++) {
            float w = mask[e] ? p[e]*sinv : 0.0f;
            wout[(size_t)n*NE + e] = w;
            if (mask[e]) bits |= (1u << e);
        }
        mbits[n] = bits;
    }
}

__global__ __launch_bounds__(256) void list_build(const unsigned int* __restrict__ mbits,
        int* __restrict__ counts, int* __restrict__ lists) {
    const int e = blockIdx.x;
    const int tid = threadIdx.x;
    const int w = tid >> 6, lane = tid & 63;
    __shared__ int wsum[4];
    __shared__ int wbase[4];
    __shared__ int basew;
    if (tid == 0) basew = 0;
    __syncthreads();
    for (int c0 = 0; c0 < NT; c0 += 256) {
        int n = c0 + tid;
        int bit = (mbits[n] >> e) & 1;
        unsigned long long m = __ballot(bit != 0);
        int pos = __popcll(m & ((1ULL << lane) - 1ULL));
        if (lane == 0) wsum[w] = __popcll(m);
        __syncthreads();
        if (tid == 0) {
            int s = basew;
            #pragma unroll
            for (int i = 0; i < 4; i++) { wbase[i] = s; s += wsum[i]; }
            basew = s;
        }
        __syncthreads();
        if (bit) lists[e*NT + wbase[w] + pos] = n;
    }
    __syncthreads();
    if (tid == 0) counts[e] = basew;
}

__global__ void scan_pad(const int* __restrict__ counts, int* __restrict__ poffs) {
    if (threadIdx.x == 0) {
        int s = 0;
        for (int e = 0; e < NE; e++) { poffs[e] = s; s += ((counts[e] + 127) >> 7) << 7; }
        poffs[NE] = s;
    }
}

__global__ void rowmap_kernel(const int* __restrict__ counts, const int* __restrict__ poffs,
                              const int* __restrict__ lists, int* __restrict__ rowtok) {
    int e = blockIdx.x; int cnt = counts[e]; int off = poffs[e];
    for (int p = threadIdx.x; p < cnt; p += 256) {
        int ri = off + p;
        if (ri < ABCAP) rowtok[ri] = lists[e*NT + p];
    }
}

template<int K>
__global__ __launch_bounds__(256) void pack_a(const float* __restrict__ src,
        const int* __restrict__ rowtok, unsigned short* __restrict__ dst) {
    const int kt = blockIdx.x;
    const int ri = blockIdx.y*64 + (threadIdx.x >> 2);
    const int t = rowtok[ri];
    if (t < 0) return;
    const int kc0 = (threadIdx.x & 3)*16;
    const float* s = src + (size_t)t*K + kt*64 + kc0;
    float4 f0 = *(const float4*)(s);
    float4 f1 = *(const float4*)(s + 4);
    float4 f2 = *(const float4*)(s + 8);
    float4 f3 = *(const float4*)(s + 12);
    unsigned short h[16] = {f2bf(f0.x), f2bf(f0.y), f2bf(f0.z), f2bf(f0.w),
                            f2bf(f1.x), f2bf(f1.y), f2bf(f1.z), f2bf(f1.w),
                            f2bf(f2.x), f2bf(f2.y), f2bf(f2.z), f2bf(f2.w),
                            f2bf(f3.x), f2bf(f3.y), f2bf(f3.z), f2bf(f3.w)};
    const int kt2 = kt*2 + (kc0 >> 5);
    const int s0 = (kc0 & 31) >> 3;
    unsigned short* d = dst + (size_t)kt2*((size_t)ABCAP*32) + (size_t)ri*32;
    *(uint4*)(d + (((s0    ) ^ SW(ri)) << 3)) = *(uint4*)&h[0];
    *(uint4*)(d + (((s0 + 1) ^ SW(ri)) << 3)) = *(uint4*)&h[8];
}

__global__ __launch_bounds__(256) void pack_b(const float* __restrict__ in,
        unsigned short* __restrict__ out, int R, int C) {
    const float* inp = in + (size_t)blockIdx.z*R*C;
    unsigned short* outp = out + (size_t)blockIdx.z*R*C;
    int kb = blockIdx.y*64, nb = blockIdx.x*64;
    __shared__ unsigned short T[64][65];
    int tid = threadIdx.x;
    int kl = tid >> 2, nl0 = (tid & 3)*16;
    const float* srcp = inp + (size_t)(kb + kl)*C + nb + nl0;
    #pragma unroll
    for (int i = 0; i < 16; i += 4) {
        float4 f = *(const float4*)(srcp + i);
        T[kl][nl0+i+0] = f2bf(f.x); T[kl][nl0+i+1] = f2bf(f.y);
        T[kl][nl0+i+2] = f2bf(f.z); T[kl][nl0+i+3] = f2bf(f.w);
    }
    __syncthreads();
    int nl = tid >> 2, kc0 = (tid & 3)*16;
    unsigned short tmp[16];
    #pragma unroll
    for (int i = 0; i < 16; i++) tmp[i] = T[kc0+i][nl];
    int n = nb + nl;
    const int kglob = kb + kc0;
    const int kt2 = kglob >> 5;
    const int s0 = (kglob & 31) >> 3;
    unsigned short* d = outp + (size_t)kt2*((size_t)C*32) + (size_t)n*32;
    *(uint4*)(d + (((s0    ) ^ SW(n)) << 3)) = *(uint4*)&tmp[0];
    *(uint4*)(d + (((s0 + 1) ^ SW(n)) << 3)) = *(uint4*)&tmp[8];
}

__global__ __launch_bounds__(256) void transpose_cvt2(const float* __restrict__ in,
        unsigned short* __restrict__ outh, unsigned short* __restrict__ outl, int R, int C) {
    const float* inp = in + (size_t)blockIdx.z*R*C;
    unsigned short* oph = outh + (size_t)blockIdx.z*R*C;
    unsigned short* opl = outl + (size_t)blockIdx.z*R*C;
    int rb = blockIdx.y*64, cb = blockIdx.x*64;
    __shared__ unsigned short Th[64][65];
    __shared__ unsigned short Tl[64][65];
    int tid = threadIdx.x;
    int lr = tid >> 2, lc0 = (tid & 3)*16;
    const float* src = inp + (size_t)(rb + lr)*C + cb + lc0;
    #pragma unroll
    for (int i = 0; i < 16; i += 4) {
        float4 f = *(const float4*)(src + i);
        float fa[4] = {f.x, f.y, f.z, f.w};
        #pragma unroll
        for (int jj = 0; jj < 4; jj++) {
            unsigned short h = f2bf(fa[jj]);
            Th[lr][lc0+i+jj] = h;
            Tl[lr][lc0+i+jj] = f2bf(fa[jj] - bf2f(h));
        }
    }
    __syncthreads();
    int oc = tid >> 2, or0 = (tid & 3)*16;
    unsigned short th[16], tl[16];
    #pragma unroll
    for (int i = 0; i < 16; i++) { th[i] = Th[or0+i][oc]; tl[i] = Tl[or0+i][oc]; }
    size_t o = (size_t)(cb+oc)*R + rb + or0;
    *(uint4*)(oph + o)     = *(uint4*)&th[0];
    *(uint4*)(oph + o + 8) = *(uint4*)&th[8];
    *(uint4*)(opl + o)     = *(uint4*)&tl[0];
    *(uint4*)(opl + o + 8) = *(uint4*)&tl[8];
}

#define GM_QKV   0
#define GM_OPROJ 1
#define GM_MOE1  2
#define GM_MOE2  3

// BK=32, 3-buffer depth-2 counted-vmcnt pipeline, raw s_barrier.
// BN=128: 4 waves 2x2 (acc 4x4, 4 loads/stage). BN=64: 4 waves 4x1 (acc 2x4,
// 3 loads/stage) — finer N-tiles double block count (TLP) w/o extra atomic bytes.
template<int MODE, int K, int N, int BN>
__global__ __launch_bounds__(256) void ggemm(
        const unsigned short* __restrict__ Apack,
        const unsigned short* __restrict__ Bt_,
        const float* __restrict__ wgt_,
        const int* __restrict__ counts_,
        const int* __restrict__ lists_,
        const int* __restrict__ poffs_,
        float* __restrict__ d0, float* __restrict__ d1, float* __restrict__ d2,
        unsigned short* __restrict__ du) {
    const int r0 = blockIdx.x*128;
    if (r0 >= poffs_[NE]) return;
    int e = 0;
    #pragma unroll
    for (int i = 1; i < NE; i++) e += (r0 >= poffs_[i]) ? 1 : 0;
    const int cnt = counts_[e];
    const int lp0 = r0 - poffs_[e];
    if (lp0 >= cnt) return;

    int n0 = 0, ktbeg = 0, ktn = K/32;
    const unsigned short* Bt = Bt_;
    float* dst = d0;
    if constexpr (MODE == GM_QKV) {
        int proj = blockIdx.y >> 1;
        ktbeg = (blockIdx.y & 1)*(K/64); ktn = K/64;     // split-K x2
        Bt = Bt_ + (size_t)proj*((size_t)NE*N*K);
        dst = (proj == 0) ? d0 : (proj == 1) ? d1 : d2;
    } else if constexpr (MODE == GM_MOE2) {
        n0 = (blockIdx.y >> 1)*BN;
        ktbeg = (blockIdx.y & 1)*(K/64); ktn = K/64;     // split-K x2 (atomic out)
    } else {
        n0 = blockIdx.y*BN;
    }
    const unsigned short* Bb = Bt + (size_t)e*N*K + (size_t)n0*32;

    constexpr int BSZ = BN*32;                 // shorts per B k-tile
    __shared__ unsigned short SA[3*4096];      // 24 KB
    __shared__ unsigned short SB[3*BSZ];       // 24 KB (BN=128) or 12 KB (BN=64)
    __shared__ int   toks[128];
    __shared__ float wro[128];
    const int tid = threadIdx.x;
    for (int i = tid; i < 128; i += 256) {
        int lp = lp0 + i; if (lp >= cnt) lp = cnt - 1;
        int t = lists_[e*NT + lp];
        toks[i] = t;
        wro[i] = wgt_[(size_t)t*NE + e];
    }

    const int lane = tid & 63, wid = tid >> 6;
    const int fr = lane & 15, ks = lane >> 4;
    // wave tiling
    constexpr int MF = (BN == 128) ? 4 : 2;    // m-frags per wave
    const int wrow = (BN == 128) ? ((wid >> 1)*64) : (wid*32);
    const int wcol = (BN == 128) ? ((wid & 1)*64) : 0;
    const int srcoffA = wid*1024 + lane*8;
    const int srcoffB = (BN == 128) ? srcoffA : (wid*512 + lane*8);

    f32x4 acc[MF][4];
    #pragma unroll
    for (int i = 0; i < MF; i++)
        #pragma unroll
        for (int j = 0; j < 4; j++) acc[i][j] = (f32x4){0.f, 0.f, 0.f, 0.f};

    #define STAGE(tt)                                                                   \
    {                                                                                   \
        const unsigned short* Asl = Apack + (size_t)(ktbeg + (tt))*((size_t)ABCAP*32)   \
                                          + (size_t)r0*32;                              \
        const unsigned short* Bsl = Bb + (size_t)(ktbeg + (tt))*((size_t)N*32);         \
        const int bu = (tt) % 3;                                                        \
        gload16(Asl + srcoffA,       &SA[bu*4096 + wid*1024]);                          \
        gload16(Asl + srcoffA + 512, &SA[bu*4096 + wid*1024 + 512]);                    \
        if constexpr (BN == 128) {                                                      \
            gload16(Bsl + srcoffB,       &SB[bu*BSZ + wid*1024]);                       \
            gload16(Bsl + srcoffB + 512, &SB[bu*BSZ + wid*1024 + 512]);                 \
        } else {                                                                        \
            gload16(Bsl + srcoffB,       &SB[bu*BSZ + wid*512]);                        \
        }                                                                               \
    }

    STAGE(0);
    if (ktn > 1) {
        STAGE(1);
        if constexpr (BN == 128) { asm volatile("s_waitcnt vmcnt(4)" ::: "memory"); }
        else                     { asm volatile("s_waitcnt vmcnt(3)" ::: "memory"); }
    } else {
        asm volatile("s_waitcnt vmcnt(0)" ::: "memory");
    }

    for (int t = 0; t < ktn; t++) {
        __builtin_amdgcn_s_barrier();          // raw barrier: in-flight loads survive
        __builtin_amdgcn_sched_barrier(0);
        if (t + 2 < ktn) STAGE(t + 2);
        if (t + 1 < ktn) {
            if constexpr (BN == 128) { asm volatile("s_waitcnt vmcnt(4)" ::: "memory"); }
            else                     { asm volatile("s_waitcnt vmcnt(3)" ::: "memory"); }
        } else {
            asm volatile("s_waitcnt vmcnt(0)" ::: "memory");
        }
        __builtin_amdgcn_sched_barrier(0);
        const int bu = t % 3;
        bf16x8 af[MF], bg[4];
        #pragma unroll
        for (int m = 0; m < MF; m++) {
            int rA = wrow + m*16 + fr;
            af[m] = *(const bf16x8*)&SA[bu*4096 + rA*32 + ((ks ^ SW(rA)) << 3)];
        }
        #pragma unroll
        for (int n = 0; n < 4; n++) {
            int rB = wcol + n*16 + fr;
            bg[n] = *(const bf16x8*)&SB[bu*BSZ + rB*32 + ((ks ^ SW(rB)) << 3)];
        }
        #pragma unroll
        for (int m = 0; m < MF; m++)
            #pragma unroll
            for (int n = 0; n < 4; n++)
                acc[m][n] = __builtin_amdgcn_mfma_f32_16x16x32_bf16(af[m], bg[n], acc[m][n], 0, 0, 0);
    }
    #undef STAGE

    #pragma unroll
    for (int m = 0; m < MF; m++) {
        #pragma unroll
        for (int rg = 0; rg < 4; rg++) {
            int lr = wrow + m*16 + ks*4 + rg;
            if (lp0 + lr >= cnt) continue;
            int t = toks[lr]; float wv = wro[lr];
            #pragma unroll
            for (int n = 0; n < 4; n++) {
                int gc = n0 + wcol + n*16 + fr;
                float v = acc[m][n][rg];
                if constexpr (MODE == GM_QKV)
                    atomicAdd(dst + (size_t)t*DDIM + gc, v*wv);
                else if constexpr (MODE == GM_OPROJ)
                    atomicAdd(dst + (size_t)t*CDIM + gc, v*wv);
                else if constexpr (MODE == GM_MOE1) {
                    int row = r0 + lr;
                    du[(size_t)(gc >> 5)*((size_t)ABCAP*32) + (size_t)row*32
                       + ((((gc >> 3) & 3) ^ SW(row)) << 3) + (gc & 7)] = f2bf(gelu_tanh(v));
                } else
                    atomicAdd(dst + (size_t)t*CDIM + gc, v*wv);
            }
        }
    }
}

__global__ void rope_cvt2(const float* __restrict__ q, const float* __restrict__ k,
        const int* __restrict__ pos_ids,
        unsigned short* __restrict__ qh, unsigned short* __restrict__ ql,
        unsigned short* __restrict__ kh, unsigned short* __restrict__ kl) {
    int n = blockIdx.x, j = threadIdx.x;
    float pos = (float)pos_ids[n];
    float inv = expf(-((float)j / 64.0f) * 9.21034037197618274f);
    float ang = pos * inv;
    float c = cosf(ang), s = sinf(ang);
    const float* qr = q + (size_t)n*DDIM;
    const float* kr = k + (size_t)n*DDIM;
    size_t base = (size_t)n*DDIM;
    float v0 = qr[j], v1 = qr[j+64];
    float a = v0*c - v1*s, b2 = v1*c + v0*s;
    unsigned short h;
    h = f2bf(a);  qh[base+j]    = h; ql[base+j]    = f2bf(a  - bf2f(h));
    h = f2bf(b2); qh[base+j+64] = h; ql[base+j+64] = f2bf(b2 - bf2f(h));
    v0 = kr[j]; v1 = kr[j+64];
    a = v0*c - v1*s; b2 = v1*c + v0*s;
    h = f2bf(a);  kh[base+j]    = h; kl[base+j]    = f2bf(a  - bf2f(h));
    h = f2bf(b2); kh[base+j+64] = h; kl[base+j+64] = f2bf(b2 - bf2f(h));
}

// LDS-staged split-precision flash attention (unchanged)
__global__ __launch_bounds__(256) void attn_part(
        const unsigned short* __restrict__ qh_, const unsigned short* __restrict__ ql_,
        const unsigned short* __restrict__ kh_, const unsigned short* __restrict__ kl_,
        const unsigned short* __restrict__ vTh, const unsigned short* __restrict__ vTl,
        float* __restrict__ Opart, float* __restrict__ ml) {
    const int qt = blockIdx.x, ch = blockIdx.y, b = blockIdx.z;
    const int qmax = qt*64 + 63;
    if (ch*128 > qmax) return;
    const int tid = threadIdx.x;
    const int w = tid >> 6, lane = tid & 63;
    const int c = lane & 15, g = lane >> 4;
    const int qrow = qt*64 + w*16 + c;
    const float scale = 0.08838834764831845f;

    __shared__ unsigned short Kh_l[64][128];
    __shared__ unsigned short Kl_l[64][128];
    __shared__ unsigned short Vh_l[128][64];
    __shared__ unsigned short Vl_l[128][64];
    __shared__ unsigned short Ph[4][16][72];
    __shared__ unsigned short Pl[4][16][72];

    bf16x8 qfh[4], qfl[4];
    const size_t qoff = ((size_t)b*TSEQ + qrow)*DDIM;
    #pragma unroll
    for (int ds = 0; ds < 4; ds++) {
        qfh[ds] = *(const bf16x8*)(qh_ + qoff + ds*32 + g*8);
        qfl[ds] = *(const bf16x8*)(ql_ + qoff + ds*32 + g*8);
    }

    f32x4 Oa[8];
    #pragma unroll
    for (int i = 0; i < 8; i++) Oa[i] = (f32x4){0.f, 0.f, 0.f, 0.f};
    float mrun = -INFINITY, lrun = 0.f;

    for (int t = 0; t < 2; t++) {
        const int kv0 = ch*128 + t*64;
        if (kv0 > qmax) break;
        if (t > 0) __syncthreads();
        #pragma unroll
        for (int i = 0; i < 4; i++) {
            int kr = w*16 + i*4 + (lane >> 4);
            int kslot = lane & 15;
            const size_t ksrc = ((size_t)b*TSEQ + kv0 + kr)*DDIM + ((size_t)(kslot ^ (kr & 7)) << 3);
            gload16(kh_ + ksrc, &Kh_l[0][0] + w*2048 + i*512 + lane*8);
            gload16(kl_ + ksrc, &Kl_l[0][0] + w*2048 + i*512 + lane*8);
            int vr = w*32 + i*8 + (lane >> 3);
            int vslot = lane & 7;
            const size_t vsrc = ((size_t)b*DDIM + vr)*TSEQ + kv0 + ((size_t)(vslot ^ (vr & 7)) << 3);
            gload16(vTh + vsrc, &Vh_l[0][0] + w*2048 + i*512 + lane*8);
            gload16(vTl + vsrc, &Vl_l[0][0] + w*2048 + i*512 + lane*8);
        }
        asm volatile("s_waitcnt vmcnt(0)" ::: "memory");
        __syncthreads();

        f32x4 Sa[4];
        #pragma unroll
        for (int m = 0; m < 4; m++) Sa[m] = (f32x4){0.f, 0.f, 0.f, 0.f};
        #pragma unroll
        for (int ds = 0; ds < 4; ds++) {
            #pragma unroll
            for (int m = 0; m < 4; m++) {
                const int lofs = (((ds*4 + g) ^ (c & 7)) << 3);
                bf16x8 kfh = *(const bf16x8*)&Kh_l[m*16 + c][lofs];
                bf16x8 kfl = *(const bf16x8*)&Kl_l[m*16 + c][lofs];
                Sa[m] = __builtin_amdgcn_mfma_f32_16x16x32_bf16(kfh, qfh[ds], Sa[m], 0, 0, 0);
                Sa[m] = __builtin_amdgcn_mfma_f32_16x16x32_bf16(kfh, qfl[ds], Sa[m], 0, 0, 0);
                Sa[m] = __builtin_amdgcn_mfma_f32_16x16x32_bf16(kfl, qfh[ds], Sa[m], 0, 0, 0);
            }
        }
        float sv[16]; float mloc = -INFINITY;
        #pragma unroll
        for (int m = 0; m < 4; m++)
            #pragma unroll
            for (int r = 0; r < 4; r++) {
                int kv = kv0 + m*16 + g*4 + r;
                float s = Sa[m][r]*scale;
                if (kv > qrow) s = -3.0e38f;
                sv[m*4+r] = s;
                mloc = fmaxf(mloc, s);
            }
        mloc = fmaxf(mloc, __shfl_xor(mloc, 16));
        mloc = fmaxf(mloc, __shfl_xor(mloc, 32));
        float mnew = fmaxf(fmaxf(mrun, mloc), -1.0e30f);
        float alpha = expf(mrun - mnew);
        float ls = 0.f;
        #pragma unroll
        for (int i = 0; i < 16; i++) { sv[i] = expf(sv[i] - mnew); ls += sv[i]; }
        ls += __shfl_xor(ls, 16); ls += __shfl_xor(ls, 32);
        lrun = lrun*alpha + ls; mrun = mnew;
        #pragma unroll
        for (int i = 0; i < 8; i++) Oa[i] *= alpha;
        #pragma unroll
        for (int m = 0; m < 4; m++) {
            unsigned short h0 = f2bf(sv[m*4+0]), h1 = f2bf(sv[m*4+1]);
            unsigned short h2 = f2bf(sv[m*4+2]), h3 = f2bf(sv[m*4+3]);
            unsigned int* ph = (unsigned int*)&Ph[w][c][m*16 + g*4];
            ph[0] = (unsigned int)h0 | ((unsigned int)h1 << 16);
            ph[1] = (unsigned int)h2 | ((unsigned int)h3 << 16);
            unsigned short l0 = f2bf(sv[m*4+0] - bf2f(h0)), l1 = f2bf(sv[m*4+1] - bf2f(h1));
            unsigned short l2 = f2bf(sv[m*4+2] - bf2f(h2)), l3 = f2bf(sv[m*4+3] - bf2f(h3));
            unsigned int* pl = (unsigned int*)&Pl[w][c][m*16 + g*4];
            pl[0] = (unsigned int)l0 | ((unsigned int)l1 << 16);
            pl[1] = (unsigned int)l2 | ((unsigned int)l3 << 16);
        }
        #pragma unroll
        for (int ksx = 0; ksx < 2; ksx++) {
            bf16x8 pfh = *(const bf16x8*)&Ph[w][c][ksx*32 + g*8];
            bf16x8 pfl = *(const bf16x8*)&Pl[w][c][ksx*32 + g*8];
            #pragma unroll
            for (int dt = 0; dt < 8; dt++) {
                const int vrow = c + dt*16;
                const int vofs = (((ksx*4 + g) ^ (vrow & 7)) << 3);
                bf16x8 vfh = *(const bf16x8*)&Vh_l[vrow][vofs];
                bf16x8 vfl = *(const bf16x8*)&Vl_l[vrow][vofs];
                Oa[dt] = __builtin_amdgcn_mfma_f32_16x16x32_bf16(vfh, pfh, Oa[dt], 0, 0, 0);
                Oa[dt] = __builtin_amdgcn_mfma_f32_16x16x32_bf16(vfh, pfl, Oa[dt], 0, 0, 0);
                Oa[dt] = __builtin_amdgcn_mfma_f32_16x16x32_bf16(vfl, pfh, Oa[dt], 0, 0, 0);
            }
        }
    }
    const size_t base = (((size_t)b*32 + qt)*16 + ch)*64;
    float* op = Opart + (base + w*16 + c)*DDIM;
    #pragma unroll
    for (int dt = 0; dt < 8; dt++)
        *(f32x4*)(op + dt*16 + g*4) = Oa[dt];
    if (g == 0) {
        float* mlp = ml + (base + w*16 + c)*2;
        mlp[0] = mrun; mlp[1] = lrun;
    }
}

__global__ __launch_bounds__(256) void attn_reduce(const float* __restrict__ Opart,
        const float* __restrict__ ml, float* __restrict__ ao) {
    const int qt = blockIdx.x, b = blockIdx.y;
    const int tid = threadIdx.x;
    const int r = tid >> 2, qq = tid & 3;
    const int nch = (qt >> 1) + 1;
    const size_t base = ((size_t)b*32 + qt)*16;
    float M = -INFINITY;
    for (int i = 0; i < nch; i++) M = fmaxf(M, ml[(base+i)*128 + r*2]);
    float L = 0.f;
    for (int i = 0; i < nch; i++)
        L += ml[(base+i)*128 + r*2 + 1]*expf(ml[(base+i)*128 + r*2] - M);
    float o[32] = {};
    for (int i = 0; i < nch; i++) {
        float sc = expf(ml[(base+i)*128 + r*2] - M);
        const float* op = Opart + ((base+i)*64 + r)*DDIM + qq;
        #pragma unroll
        for (int m2 = 0; m2 < 32; m2++) o[m2] += sc*op[4*m2];
    }
    float linv = 1.0f / L;
    float* dst = ao + ((size_t)b*TSEQ + qt*64 + r)*DDIM + qq;
    #pragma unroll
    for (int m2 = 0; m2 < 32; m2++) dst[4*m2] = o[m2]*linv;
}

extern "C" void kernel_launch(void* const* d_in, const int* in_sizes, int n_in,
                              void* d_out, int out_size, void* d_ws, size_t ws_size,
                              hipStream_t stream) {
    const float* x     = (const float*)d_in[0];
    const int*   pos   = (const int*)d_in[1];
    const float* asim  = (const float*)d_in[2];
    const float* agate = (const float*)d_in[3];
    const float* qw    = (const float*)d_in[4];
    const float* kw    = (const float*)d_in[5];
    const float* vw    = (const float*)d_in[6];
    const float* ow    = (const float*)d_in[7];
    const float* msim  = (const float*)d_in[8];
    const float* mgate = (const float*)d_in[9];
    const float* w1    = (const float*)d_in[10];
    const float* w2    = (const float*)d_in[11];
    const int*   kqa   = (const int*)d_in[12];
    const int*   kqm   = (const int*)d_in[13];

    char* ws = (char*)d_ws;
    int*   counts_a = (int*)(ws + OFF_CA);
    int*   counts_m = (int*)(ws + OFF_CM);
    float* colinv   = (float*)(ws + OFF_CI);
    int*   poffs_a  = (int*)(ws + OFF_PA);
    int*   poffs_m  = (int*)(ws + OFF_PM);
    float* w_a      = (float*)(ws + OFF_WA);
    float* w_m      = (float*)(ws + OFF_WM);
    int*   list_a   = (int*)(ws + OFF_LA);
    int*   list_m   = (int*)(ws + OFF_LM);
    int*   rowtok_a = (int*)(ws + OFF_RTA);
    int*   rowtok_m = (int*)(ws + OFF_RTM);
    unsigned int* mb_a = (unsigned int*)(ws + OFF_MBA);
    unsigned int* mb_m = (unsigned int*)(ws + OFF_MBM);
    float* qb   = (float*)(ws + OFF_QB);
    float* kb   = (float*)(ws + OFF_KB);
    float* vb   = (float*)(ws + OFF_VB);
    float* ao   = (float*)(ws + OFF_AO);
    unsigned short* qhi = (unsigned short*)(ws + OFF_QHI);
    unsigned short* qlo = (unsigned short*)(ws + OFF_QLO);
    unsigned short* khi = (unsigned short*)(ws + OFF_KHI);
    unsigned short* klo = (unsigned short*)(ws + OFF_KLO);
    unsigned short* vTh = (unsigned short*)(ws + OFF_VTH);
    unsigned short* vTl = (unsigned short*)(ws + OFF_VTL);
    float* mlb  = (float*)(ws + OFF_ML);
    unsigned short* wqkvt = (unsigned short*)(ws + OFF_WQKVT);
    unsigned short* wot   = (unsigned short*)(ws + OFF_WOT);
    unsigned short* apop  = (unsigned short*)(ws + OFF_APOP);
    unsigned short* apqkv = (unsigned short*)(ws + OFF_APQKV);
    float* Opart = (float*)(ws + OFF_OP);
    unsigned short* apm   = (unsigned short*)(ws + OFF_APM);
    unsigned short* w1t   = (unsigned short*)(ws + OFF_W1T);
    unsigned short* ab2   = (unsigned short*)(ws + OFF_AB2);
    float* out = (float*)d_out;

    (void)hipMemsetAsync(ws + OFF_CA, 0, 512, stream);
    (void)hipMemsetAsync(ws + OFF_RTA, 0xFF, 64*1024, stream);
    (void)hipMemsetAsync(ws + OFF_QB, 0, MB(6), stream);

    colnorm_kernel<<<16, 256, 0, stream>>>(asim, msim, colinv);

    gating_kernel<<<NT, 256, 0, stream>>>(x, asim, agate, colinv, kqa, w_a, mb_a);
    list_build<<<NE, 256, 0, stream>>>(mb_a, counts_a, list_a);
    scan_pad<<<1, 64, 0, stream>>>(counts_a, poffs_a);
    rowmap_kernel<<<NE, 256, 0, stream>>>(counts_a, poffs_a, list_a, rowtok_a);
    pack_a<CDIM><<<dim3(16, ABCAP/64), 256, 0, stream>>>(x, rowtok_a, apqkv);
    pack_b<<<dim3(2, 16, NE), 256, 0, stream>>>(qw, wqkvt,                          CDIM, DDIM);
    pack_b<<<dim3(2, 16, NE), 256, 0, stream>>>(kw, wqkvt + (size_t)NE*CDIM*DDIM,   CDIM, DDIM);
    pack_b<<<dim3(2, 16, NE), 256, 0, stream>>>(vw, wqkvt + (size_t)2*NE*CDIM*DDIM, CDIM, DDIM);
    ggemm<GM_QKV, CDIM, DDIM, 128><<<dim3(NTIL, 6), 256, 0, stream>>>(
        apqkv, wqkvt, w_a, counts_a, list_a, poffs_a, qb, kb, vb, nullptr);
    rope_cvt2<<<NT, 64, 0, stream>>>(qb, kb, pos, qhi, qlo, khi, klo);
    transpose_cvt2<<<dim3(2, 32, NB), 256, 0, stream>>>(vb, vTh, vTl, TSEQ, DDIM);
    attn_part<<<dim3(32, 16, NB), 256, 0, stream>>>(qhi, qlo, khi, klo, vTh, vTl, Opart, mlb);
    attn_reduce<<<dim3(32, NB), 256, 0, stream>>>(Opart, mlb, ao);

    pack_a<DDIM><<<dim3(2, ABCAP/64), 256, 0, stream>>>(ao, rowtok_a, apop);
    pack_b<<<dim3(16, 2, NE), 256, 0, stream>>>(ow, wot, DDIM, CDIM);
    (void)hipMemcpyAsync(out, x, (size_t)NT*CDIM*4, hipMemcpyDeviceToDevice, stream);
    ggemm<GM_OPROJ, DDIM, CDIM, 128><<<dim3(NTIL, 8), 256, 0, stream>>>(
        apop, wot, w_a, counts_a, list_a, poffs_a, out, nullptr, nullptr, nullptr);

    gating_kernel<<<NT, 256, 0, stream>>>(out, msim, mgate, colinv + NE, kqm, w_m, mb_m);
    list_build<<<NE, 256, 0, stream>>>(mb_m, counts_m, list_m);
    scan_pad<<<1, 64, 0, stream>>>(counts_m, poffs_m);
    rowmap_kernel<<<NE, 256, 0, stream>>>(counts_m, poffs_m, list_m, rowtok_m);
    pack_a<CDIM><<<dim3(16, ABCAP/64), 256, 0, stream>>>(out, rowtok_m, apm);
    pack_b<<<dim3(32, 16, NE), 256, 0, stream>>>(w1, w1t, CDIM, FFDIM);
    ggemm<GM_MOE1, CDIM, FFDIM, 64><<<dim3(NTIL, 32), 256, 0, stream>>>(
        apm, w1t, w_m, counts_m, list_m, poffs_m, nullptr, nullptr, nullptr, ab2);
    pack_b<<<dim3(16, 32, NE), 256, 0, stream>>>(w2, w1t, FFDIM, CDIM);
    ggemm<GM_MOE2, FFDIM, CDIM, 64><<<dim3(NTIL, 32), 256, 0, stream>>>(
        ab2, w1t, w_m, counts_m, list_m, poffs_m, out, nullptr, nullptr, nullptr);
}

// Round 21
// 350.884 us; speedup vs baseline: 1.0493x; 1.0493x over previous
//
#include <hip/hip_runtime.h>
#include <cstdint>

#define NB   2
#define TSEQ 2048
#define NT   4096
#define CDIM 1024
#define DDIM 128
#define FFDIM 2048
#define NE   8
#define ABCAP 8192
#define NTIL 40

#define MB(x) ((size_t)(x) << 20)

#define OFF_CA   ((size_t)0)
#define OFF_CM   ((size_t)64)
#define OFF_CI   ((size_t)128)
#define OFF_PA   ((size_t)256)
#define OFF_PM   ((size_t)320)
#define OFF_WA   ((size_t)1024)
#define OFF_WM   (OFF_WA + (size_t)NT*NE*4)
#define OFF_LA   (OFF_WM + (size_t)NT*NE*4)
#define OFF_LM   (OFF_LA + (size_t)NT*NE*4)
#define OFF_RTA  ((size_t)600*1024)
#define OFF_RTM  ((size_t)632*1024)
#define OFF_MBA  ((size_t)664*1024)
#define OFF_MBM  ((size_t)680*1024)
#define OFF_QB   MB(1)
#define OFF_KB   MB(3)
#define OFF_VB   MB(5)
#define OFF_AO   MB(7)
#define OFF_QHI  MB(9)
#define OFF_QLO  MB(10)
#define OFF_KHI  MB(11)
#define OFF_KLO  MB(12)
#define OFF_VTH  MB(13)
#define OFF_VTL  MB(14)
#define OFF_ML   MB(15)
#define OFF_WQKVT MB(16)
#define OFF_WOT  MB(22)
#define OFF_APOP MB(24)
#define OFF_APQKV MB(26)
#define OFF_OP   MB(26)
#define OFF_APM  MB(59)
#define OFF_W1T  MB(75)
#define OFF_AB2  MB(107)

typedef __attribute__((ext_vector_type(8))) short bf16x8;
typedef __attribute__((ext_vector_type(4))) float f32x4;

#define SW(r) (((r) >> 1) & 3)

__device__ __forceinline__ float gelu_tanh(float x) {
    float x3 = x*x*x;
    float z2 = 1.5957691216057308f*(x + 0.044715f*x3);
    float t = 1.0f - 2.0f/(__expf(z2) + 1.0f);
    return 0.5f*x*(1.0f + t);
}

__device__ __forceinline__ unsigned short f2bf(float f) {
    union { float f; uint32_t u; } v; v.f = f;
    uint32_t r = (v.u + 0x7fff + ((v.u >> 16) & 1)) >> 16;
    return (unsigned short)r;
}
__device__ __forceinline__ float bf2f(unsigned short h) {
    union { uint32_t u; float f; } v; v.u = ((uint32_t)h) << 16; return v.f;
}

__device__ __forceinline__ void gload16(const unsigned short* g, unsigned short* l) {
    __builtin_amdgcn_global_load_lds(
        (const __attribute__((address_space(1))) void*)g,
        (__attribute__((address_space(3))) void*)l,
        16, 0, 0);
}

__global__ void colnorm_kernel(const float* __restrict__ asim,
                               const float* __restrict__ msim,
                               float* __restrict__ inv) {
    int col = blockIdx.x;
    const float* s = (col < NE) ? asim : msim;
    int e = col & (NE-1);
    int tid = threadIdx.x;
    float ss = 0.0f;
    for (int c = tid; c < CDIM; c += 256) { float v = s[(size_t)c*NE + e]; ss += v*v; }
    __shared__ float red[256];
    red[tid] = ss; __syncthreads();
    for (int st = 128; st > 0; st >>= 1) { if (tid < st) red[tid] += red[tid+st]; __syncthreads(); }
    if (tid == 0) inv[col] = 1.0f / fmaxf(sqrtf(red[0]), 1e-12f);
}

// gating: writes per-token expert bitmask (no atomics)
__global__ void gating_kernel(const float* __restrict__ xin,
                              const float* __restrict__ sim,
                              const float* __restrict__ gates,
                              const float* __restrict__ colinv,
                              const int* __restrict__ kmin_p,
                              float* __restrict__ wout,
                              unsigned int* __restrict__ mbits) {
    const int n = blockIdx.x, tid = threadIdx.x;
    const float* xr = xin + (size_t)n*CDIM;
    float4 xv = *(const float4*)(xr + tid*4);
    float acc[9];
    acc[0] = xv.x*xv.x + xv.y*xv.y + xv.z*xv.z + xv.w*xv.w;
    int c = tid*4;
    #pragma unroll
    for (int e = 0; e < NE; e++)
        acc[1+e] = xv.x*sim[(size_t)(c+0)*NE+e] + xv.y*sim[(size_t)(c+1)*NE+e]
                 + xv.z*sim[(size_t)(c+2)*NE+e] + xv.w*sim[(size_t)(c+3)*NE+e];
    __shared__ float red[9][256];
    #pragma unroll
    for (int a = 0; a < 9; a++) red[a][tid] = acc[a];
    __syncthreads();
    for (int s = 128; s > 0; s >>= 1) {
        if (tid < s) {
            #pragma unroll
            for (int a = 0; a < 9; a++) red[a][tid] += red[a][tid+s];
        }
        __syncthreads();
    }
    if (tid == 0) {
        float xinv = 1.0f / fmaxf(sqrtf(red[0][0]), 1e-12f);
        float logits[NE], gated[NE];
        int mask[NE]; int any = 0;
        #pragma unroll
        for (int e = 0; e < NE; e++) {
            float lg = red[1+e][0]*xinv*colinv[e] - 1.0f/(1.0f + expf(-gates[e]));
            logits[e] = lg; gated[e] = fmaxf(lg, 0.0f);
            mask[e] = (lg > 0.0f) ? 1 : 0; any |= mask[e];
        }
        if (!any) {
            int kmin = *kmin_p; if (kmin < 1) kmin = 1; if (kmin > NE) kmin = NE;
            int used[NE] = {0,0,0,0,0,0,0,0};
            for (int kk = 0; kk < kmin; kk++) {
                int best = -1; float bv = 0.0f;
                for (int e = 0; e < NE; e++)
                    if (!used[e] && (best < 0 || logits[e] > bv)) { best = e; bv = logits[e]; }
                used[best] = 1; mask[best] = 1;
            }
        }
        float mx = -3.402823466e38f;
        #pragma unroll
        for (int e = 0; e < NE; e++) { float me = mask[e] ? gated[e] : -1.0e9f; mx = fmaxf(mx, me); }
        float sum = 0.0f, p[NE];
        #pragma unroll
        for (int e = 0; e < NE; e++) { p[e] = expf((mask[e] ? gated[e] : -1.0e9f) - mx); sum += p[e]; }
        float sinv = 1.0f / sum;
        unsigned int bits = 0;
        #pragma unroll
        for (int e = 0; e < NE; e++) {
            float w = mask[e] ? p[e]*sinv : 0.0f;
            wout[(size_t)n*NE + e] = w;
            if (mask[e]) bits |= (1u << e);
        }
        mbits[n] = bits;
    }
}

__global__ __launch_bounds__(256) void list_build(const unsigned int* __restrict__ mbits,
        int* __restrict__ counts, int* __restrict__ lists) {
    const int e = blockIdx.x;
    const int tid = threadIdx.x;
    const int w = tid >> 6, lane = tid & 63;
    __shared__ int wsum[4];
    __shared__ int wbase[4];
    __shared__ int basew;
    if (tid == 0) basew = 0;
    __syncthreads();
    for (int c0 = 0; c0 < NT; c0 += 256) {
        int n = c0 + tid;
        int bit = (mbits[n] >> e) & 1;
        unsigned long long m = __ballot(bit != 0);
        int pos = __popcll(m & ((1ULL << lane) - 1ULL));
        if (lane == 0) wsum[w] = __popcll(m);
        __syncthreads();
        if (tid == 0) {
            int s = basew;
            #pragma unroll
            for (int i = 0; i < 4; i++) { wbase[i] = s; s += wsum[i]; }
            basew = s;
        }
        __syncthreads();
        if (bit) lists[e*NT + wbase[w] + pos] = n;
    }
    __syncthreads();
    if (tid == 0) counts[e] = basew;
}

__global__ void scan_pad(const int* __restrict__ counts, int* __restrict__ poffs) {
    if (threadIdx.x == 0) {
        int s = 0;
        for (int e = 0; e < NE; e++) { poffs[e] = s; s += ((counts[e] + 127) >> 7) << 7; }
        poffs[NE] = s;
    }
}

__global__ void rowmap_kernel(const int* __restrict__ counts, const int* __restrict__ poffs,
                              const int* __restrict__ lists, int* __restrict__ rowtok) {
    int e = blockIdx.x; int cnt = counts[e]; int off = poffs[e];
    for (int p = threadIdx.x; p < cnt; p += 256) {
        int ri = off + p;
        if (ri < ABCAP) rowtok[ri] = lists[e*NT + p];
    }
}

template<int K>
__global__ __launch_bounds__(256) void pack_a(const float* __restrict__ src,
        const int* __restrict__ rowtok, unsigned short* __restrict__ dst) {
    const int kt = blockIdx.x;
    const int ri = blockIdx.y*64 + (threadIdx.x >> 2);
    const int t = rowtok[ri];
    if (t < 0) return;
    const int kc0 = (threadIdx.x & 3)*16;
    const float* s = src + (size_t)t*K + kt*64 + kc0;
    float4 f0 = *(const float4*)(s);
    float4 f1 = *(const float4*)(s + 4);
    float4 f2 = *(const float4*)(s + 8);
    float4 f3 = *(const float4*)(s + 12);
    unsigned short h[16] = {f2bf(f0.x), f2bf(f0.y), f2bf(f0.z), f2bf(f0.w),
                            f2bf(f1.x), f2bf(f1.y), f2bf(f1.z), f2bf(f1.w),
                            f2bf(f2.x), f2bf(f2.y), f2bf(f2.z), f2bf(f2.w),
                            f2bf(f3.x), f2bf(f3.y), f2bf(f3.z), f2bf(f3.w)};
    const int kt2 = kt*2 + (kc0 >> 5);
    const int s0 = (kc0 & 31) >> 3;
    unsigned short* d = dst + (size_t)kt2*((size_t)ABCAP*32) + (size_t)ri*32;
    *(uint4*)(d + (((s0    ) ^ SW(ri)) << 3)) = *(uint4*)&h[0];
    *(uint4*)(d + (((s0 + 1) ^ SW(ri)) << 3)) = *(uint4*)&h[8];
}

__global__ __launch_bounds__(256) void pack_b(const float* __restrict__ in,
        unsigned short* __restrict__ out, int R, int C) {
    const float* inp = in + (size_t)blockIdx.z*R*C;
    unsigned short* outp = out + (size_t)blockIdx.z*R*C;
    int kb = blockIdx.y*64, nb = blockIdx.x*64;
    __shared__ unsigned short T[64][65];
    int tid = threadIdx.x;
    int kl = tid >> 2, nl0 = (tid & 3)*16;
    const float* srcp = inp + (size_t)(kb + kl)*C + nb + nl0;
    #pragma unroll
    for (int i = 0; i < 16; i += 4) {
        float4 f = *(const float4*)(srcp + i);
        T[kl][nl0+i+0] = f2bf(f.x); T[kl][nl0+i+1] = f2bf(f.y);
        T[kl][nl0+i+2] = f2bf(f.z); T[kl][nl0+i+3] = f2bf(f.w);
    }
    __syncthreads();
    int nl = tid >> 2, kc0 = (tid & 3)*16;
    unsigned short tmp[16];
    #pragma unroll
    for (int i = 0; i < 16; i++) tmp[i] = T[kc0+i][nl];
    int n = nb + nl;
    const int kglob = kb + kc0;
    const int kt2 = kglob >> 5;
    const int s0 = (kglob & 31) >> 3;
    unsigned short* d = outp + (size_t)kt2*((size_t)C*32) + (size_t)n*32;
    *(uint4*)(d + (((s0    ) ^ SW(n)) << 3)) = *(uint4*)&tmp[0];
    *(uint4*)(d + (((s0 + 1) ^ SW(n)) << 3)) = *(uint4*)&tmp[8];
}

__global__ __launch_bounds__(256) void transpose_cvt2(const float* __restrict__ in,
        unsigned short* __restrict__ outh, unsigned short* __restrict__ outl, int R, int C) {
    const float* inp = in + (size_t)blockIdx.z*R*C;
    unsigned short* oph = outh + (size_t)blockIdx.z*R*C;
    unsigned short* opl = outl + (size_t)blockIdx.z*R*C;
    int rb = blockIdx.y*64, cb = blockIdx.x*64;
    __shared__ unsigned short Th[64][65];
    __shared__ unsigned short Tl[64][65];
    int tid = threadIdx.x;
    int lr = tid >> 2, lc0 = (tid & 3)*16;
    const float* src = inp + (size_t)(rb + lr)*C + cb + lc0;
    #pragma unroll
    for (int i = 0; i < 16; i += 4) {
        float4 f = *(const float4*)(src + i);
        float fa[4] = {f.x, f.y, f.z, f.w};
        #pragma unroll
        for (int jj = 0; jj < 4; jj++) {
            unsigned short h = f2bf(fa[jj]);
            Th[lr][lc0+i+jj] = h;
            Tl[lr][lc0+i+jj] = f2bf(fa[jj] - bf2f(h));
        }
    }
    __syncthreads();
    int oc = tid >> 2, or0 = (tid & 3)*16;
    unsigned short th[16], tl[16];
    #pragma unroll
    for (int i = 0; i < 16; i++) { th[i] = Th[or0+i][oc]; tl[i] = Tl[or0+i][oc]; }
    size_t o = (size_t)(cb+oc)*R + rb + or0;
    *(uint4*)(oph + o)     = *(uint4*)&th[0];
    *(uint4*)(oph + o + 8) = *(uint4*)&th[8];
    *(uint4*)(opl + o)     = *(uint4*)&tl[0];
    *(uint4*)(opl + o + 8) = *(uint4*)&tl[8];
}

#define GM_QKV   0
#define GM_OPROJ 1
#define GM_MOE1  2
#define GM_MOE2  3

// BK=32, 3-buffer depth-2 pipeline, counted vmcnt(4), RAW s_barrier (T4).
// Round-19 configuration: BN=128 everywhere (measured optimum).
template<int MODE, int K, int N>
__global__ __launch_bounds__(256) void ggemm(
        const unsigned short* __restrict__ Apack,
        const unsigned short* __restrict__ Bt_,
        const float* __restrict__ wgt_,
        const int* __restrict__ counts_,
        const int* __restrict__ lists_,
        const int* __restrict__ poffs_,
        float* __restrict__ d0, float* __restrict__ d1, float* __restrict__ d2,
        unsigned short* __restrict__ du) {
    const int r0 = blockIdx.x*128;
    if (r0 >= poffs_[NE]) return;
    int e = 0;
    #pragma unroll
    for (int i = 1; i < NE; i++) e += (r0 >= poffs_[i]) ? 1 : 0;
    const int cnt = counts_[e];
    const int lp0 = r0 - poffs_[e];
    if (lp0 >= cnt) return;

    int n0 = 0, ktbeg = 0, ktn = K/32;
    const unsigned short* Bt = Bt_;
    float* dst = d0;
    if constexpr (MODE == GM_QKV) {
        int proj = blockIdx.y >> 1;
        ktbeg = (blockIdx.y & 1)*(K/64); ktn = K/64;     // split-K x2
        Bt = Bt_ + (size_t)proj*((size_t)NE*N*K);
        dst = (proj == 0) ? d0 : (proj == 1) ? d1 : d2;
    } else if constexpr (MODE == GM_MOE2) {
        n0 = (blockIdx.y >> 1)*128;
        ktbeg = (blockIdx.y & 1)*(K/64); ktn = K/64;     // split-K x2 (atomic out)
    } else {
        n0 = blockIdx.y*128;
    }
    const unsigned short* Bb = Bt + (size_t)e*N*K + (size_t)n0*32;

    __shared__ unsigned short SA[3*4096];   // 24 KB
    __shared__ unsigned short SB[3*4096];   // 24 KB
    __shared__ int   toks[128];
    __shared__ float wro[128];
    const int tid = threadIdx.x;
    for (int i = tid; i < 128; i += 256) {
        int lp = lp0 + i; if (lp >= cnt) lp = cnt - 1;
        int t = lists_[e*NT + lp];
        toks[i] = t;
        wro[i] = wgt_[(size_t)t*NE + e];
    }

    const int lane = tid & 63, wid = tid >> 6;
    const int wr = wid >> 1, wc = wid & 1;
    const int fr = lane & 15, ks = lane >> 4;
    const int srcoff = wid*1024 + lane*8;

    f32x4 acc[4][4];
    #pragma unroll
    for (int i = 0; i < 4; i++)
        #pragma unroll
        for (int j = 0; j < 4; j++) acc[i][j] = (f32x4){0.f, 0.f, 0.f, 0.f};

    #define STAGE(tt)                                                                   \
    {                                                                                   \
        const unsigned short* Asl = Apack + (size_t)(ktbeg + (tt))*((size_t)ABCAP*32)   \
                                          + (size_t)r0*32;                              \
        const unsigned short* Bsl = Bb + (size_t)(ktbeg + (tt))*((size_t)N*32);         \
        const int bu = (tt) % 3;                                                        \
        gload16(Asl + srcoff,       &SA[bu*4096 + wid*1024]);                           \
        gload16(Asl + srcoff + 512, &SA[bu*4096 + wid*1024 + 512]);                     \
        gload16(Bsl + srcoff,       &SB[bu*4096 + wid*1024]);                           \
        gload16(Bsl + srcoff + 512, &SB[bu*4096 + wid*1024 + 512]);                     \
    }

    STAGE(0);
    if (ktn > 1) {
        STAGE(1);
        asm volatile("s_waitcnt vmcnt(4)" ::: "memory");
    } else {
        asm volatile("s_waitcnt vmcnt(0)" ::: "memory");
    }

    for (int t = 0; t < ktn; t++) {
        __builtin_amdgcn_s_barrier();          // raw barrier: in-flight loads survive
        __builtin_amdgcn_sched_barrier(0);
        if (t + 2 < ktn) STAGE(t + 2);
        if (t + 1 < ktn) { asm volatile("s_waitcnt vmcnt(4)" ::: "memory"); }
        else             { asm volatile("s_waitcnt vmcnt(0)" ::: "memory"); }
        __builtin_amdgcn_sched_barrier(0);
        const int bu = t % 3;
        bf16x8 af[4], bg[4];
        #pragma unroll
        for (int m = 0; m < 4; m++) {
            int rA = wr*64 + m*16 + fr;
            af[m] = *(const bf16x8*)&SA[bu*4096 + rA*32 + ((ks ^ SW(rA)) << 3)];
        }
        #pragma unroll
        for (int n = 0; n < 4; n++) {
            int rB = wc*64 + n*16 + fr;
            bg[n] = *(const bf16x8*)&SB[bu*4096 + rB*32 + ((ks ^ SW(rB)) << 3)];
        }
        #pragma unroll
        for (int m = 0; m < 4; m++)
            #pragma unroll
            for (int n = 0; n < 4; n++)
                acc[m][n] = __builtin_amdgcn_mfma_f32_16x16x32_bf16(af[m], bg[n], acc[m][n], 0, 0, 0);
    }
    #undef STAGE

    #pragma unroll
    for (int m = 0; m < 4; m++) {
        #pragma unroll
        for (int rg = 0; rg < 4; rg++) {
            int lr = wr*64 + m*16 + ks*4 + rg;
            if (lp0 + lr >= cnt) continue;
            int t = toks[lr]; float wv = wro[lr];
            #pragma unroll
            for (int n = 0; n < 4; n++) {
                int gc = n0 + wc*64 + n*16 + fr;
                float v = acc[m][n][rg];
                if constexpr (MODE == GM_QKV)
                    atomicAdd(dst + (size_t)t*DDIM + gc, v*wv);
                else if constexpr (MODE == GM_OPROJ)
                    atomicAdd(dst + (size_t)t*CDIM + gc, v*wv);
                else if constexpr (MODE == GM_MOE1) {
                    int row = r0 + lr;
                    du[(size_t)(gc >> 5)*((size_t)ABCAP*32) + (size_t)row*32
                       + ((((gc >> 3) & 3) ^ SW(row)) << 3) + (gc & 7)] = f2bf(gelu_tanh(v));
                } else
                    atomicAdd(dst + (size_t)t*CDIM + gc, v*wv);
            }
        }
    }
}

__global__ void rope_cvt2(const float* __restrict__ q, const float* __restrict__ k,
        const int* __restrict__ pos_ids,
        unsigned short* __restrict__ qh, unsigned short* __restrict__ ql,
        unsigned short* __restrict__ kh, unsigned short* __restrict__ kl) {
    int n = blockIdx.x, j = threadIdx.x;
    float pos = (float)pos_ids[n];
    float inv = expf(-((float)j / 64.0f) * 9.21034037197618274f);
    float ang = pos * inv;
    float c = cosf(ang), s = sinf(ang);
    const float* qr = q + (size_t)n*DDIM;
    const float* kr = k + (size_t)n*DDIM;
    size_t base = (size_t)n*DDIM;
    float v0 = qr[j], v1 = qr[j+64];
    float a = v0*c - v1*s, b2 = v1*c + v0*s;
    unsigned short h;
    h = f2bf(a);  qh[base+j]    = h; ql[base+j]    = f2bf(a  - bf2f(h));
    h = f2bf(b2); qh[base+j+64] = h; ql[base+j+64] = f2bf(b2 - bf2f(h));
    v0 = kr[j]; v1 = kr[j+64];
    a = v0*c - v1*s; b2 = v1*c + v0*s;
    h = f2bf(a);  kh[base+j]    = h; kl[base+j]    = f2bf(a  - bf2f(h));
    h = f2bf(b2); kh[base+j+64] = h; kl[base+j+64] = f2bf(b2 - bf2f(h));
}

// LDS-staged split-precision flash attention
__global__ __launch_bounds__(256) void attn_part(
        const unsigned short* __restrict__ qh_, const unsigned short* __restrict__ ql_,
        const unsigned short* __restrict__ kh_, const unsigned short* __restrict__ kl_,
        const unsigned short* __restrict__ vTh, const unsigned short* __restrict__ vTl,
        float* __restrict__ Opart, float* __restrict__ ml) {
    const int qt = blockIdx.x, ch = blockIdx.y, b = blockIdx.z;
    const int qmax = qt*64 + 63;
    if (ch*128 > qmax) return;
    const int tid = threadIdx.x;
    const int w = tid >> 6, lane = tid & 63;
    const int c = lane & 15, g = lane >> 4;
    const int qrow = qt*64 + w*16 + c;
    const float scale = 0.08838834764831845f;

    __shared__ unsigned short Kh_l[64][128];
    __shared__ unsigned short Kl_l[64][128];
    __shared__ unsigned short Vh_l[128][64];
    __shared__ unsigned short Vl_l[128][64];
    __shared__ unsigned short Ph[4][16][72];
    __shared__ unsigned short Pl[4][16][72];

    bf16x8 qfh[4], qfl[4];
    const size_t qoff = ((size_t)b*TSEQ + qrow)*DDIM;
    #pragma unroll
    for (int ds = 0; ds < 4; ds++) {
        qfh[ds] = *(const bf16x8*)(qh_ + qoff + ds*32 + g*8);
        qfl[ds] = *(const bf16x8*)(ql_ + qoff + ds*32 + g*8);
    }

    f32x4 Oa[8];
    #pragma unroll
    for (int i = 0; i < 8; i++) Oa[i] = (f32x4){0.f, 0.f, 0.f, 0.f};
    float mrun = -INFINITY, lrun = 0.f;

    for (int t = 0; t < 2; t++) {
        const int kv0 = ch*128 + t*64;
        if (kv0 > qmax) break;
        if (t > 0) __syncthreads();
        #pragma unroll
        for (int i = 0; i < 4; i++) {
            int kr = w*16 + i*4 + (lane >> 4);
            int kslot = lane & 15;
            const size_t ksrc = ((size_t)b*TSEQ + kv0 + kr)*DDIM + ((size_t)(kslot ^ (kr & 7)) << 3);
            gload16(kh_ + ksrc, &Kh_l[0][0] + w*2048 + i*512 + lane*8);
            gload16(kl_ + ksrc, &Kl_l[0][0] + w*2048 + i*512 + lane*8);
            int vr = w*32 + i*8 + (lane >> 3);
            int vslot = lane & 7;
            const size_t vsrc = ((size_t)b*DDIM + vr)*TSEQ + kv0 + ((size_t)(vslot ^ (vr & 7)) << 3);
            gload16(vTh + vsrc, &Vh_l[0][0] + w*2048 + i*512 + lane*8);
            gload16(vTl + vsrc, &Vl_l[0][0] + w*2048 + i*512 + lane*8);
        }
        asm volatile("s_waitcnt vmcnt(0)" ::: "memory");
        __syncthreads();

        f32x4 Sa[4];
        #pragma unroll
        for (int m = 0; m < 4; m++) Sa[m] = (f32x4){0.f, 0.f, 0.f, 0.f};
        #pragma unroll
        for (int ds = 0; ds < 4; ds++) {
            #pragma unroll
            for (int m = 0; m < 4; m++) {
                const int lofs = (((ds*4 + g) ^ (c & 7)) << 3);
                bf16x8 kfh = *(const bf16x8*)&Kh_l[m*16 + c][lofs];
                bf16x8 kfl = *(const bf16x8*)&Kl_l[m*16 + c][lofs];
                Sa[m] = __builtin_amdgcn_mfma_f32_16x16x32_bf16(kfh, qfh[ds], Sa[m], 0, 0, 0);
                Sa[m] = __builtin_amdgcn_mfma_f32_16x16x32_bf16(kfh, qfl[ds], Sa[m], 0, 0, 0);
                Sa[m] = __builtin_amdgcn_mfma_f32_16x16x32_bf16(kfl, qfh[ds], Sa[m], 0, 0, 0);
            }
        }
        float sv[16]; float mloc = -INFINITY;
        #pragma unroll
        for (int m = 0; m < 4; m++)
            #pragma unroll
            for (int r = 0; r < 4; r++) {
                int kv = kv0 + m*16 + g*4 + r;
                float s = Sa[m][r]*scale;
                if (kv > qrow) s = -3.0e38f;
                sv[m*4+r] = s;
                mloc = fmaxf(mloc, s);
            }
        mloc = fmaxf(mloc, __shfl_xor(mloc, 16));
        mloc = fmaxf(mloc, __shfl_xor(mloc, 32));
        float mnew = fmaxf(fmaxf(mrun, mloc), -1.0e30f);
        float alpha = expf(mrun - mnew);
        float ls = 0.f;
        #pragma unroll
        for (int i = 0; i < 16; i++) { sv[i] = expf(sv[i] - mnew); ls += sv[i]; }
        ls += __shfl_xor(ls, 16); ls += __shfl_xor(ls, 32);
        lrun = lrun*alpha + ls; mrun = mnew;
        #pragma unroll
        for (int i = 0; i < 8; i++) Oa[i] *= alpha;
        #pragma unroll
        for (int m = 0; m < 4; m++) {
            unsigned short h0 = f2bf(sv[m*4+0]), h1 = f2bf(sv[m*4+1]);
            unsigned short h2 = f2bf(sv[m*4+2]), h3 = f2bf(sv[m*4+3]);
            unsigned int* ph = (unsigned int*)&Ph[w][c][m*16 + g*4];
            ph[0] = (unsigned int)h0 | ((unsigned int)h1 << 16);
            ph[1] = (unsigned int)h2 | ((unsigned int)h3 << 16);
            unsigned short l0 = f2bf(sv[m*4+0] - bf2f(h0)), l1 = f2bf(sv[m*4+1] - bf2f(h1));
            unsigned short l2 = f2bf(sv[m*4+2] - bf2f(h2)), l3 = f2bf(sv[m*4+3] - bf2f(h3));
            unsigned int* pl = (unsigned int*)&Pl[w][c][m*16 + g*4];
            pl[0] = (unsigned int)l0 | ((unsigned int)l1 << 16);
            pl[1] = (unsigned int)l2 | ((unsigned int)l3 << 16);
        }
        #pragma unroll
        for (int ksx = 0; ksx < 2; ksx++) {
            bf16x8 pfh = *(const bf16x8*)&Ph[w][c][ksx*32 + g*8];
            bf16x8 pfl = *(const bf16x8*)&Pl[w][c][ksx*32 + g*8];
            #pragma unroll
            for (int dt = 0; dt < 8; dt++) {
                const int vrow = c + dt*16;
                const int vofs = (((ksx*4 + g) ^ (vrow & 7)) << 3);
                bf16x8 vfh = *(const bf16x8*)&Vh_l[vrow][vofs];
                bf16x8 vfl = *(const bf16x8*)&Vl_l[vrow][vofs];
                Oa[dt] = __builtin_amdgcn_mfma_f32_16x16x32_bf16(vfh, pfh, Oa[dt], 0, 0, 0);
                Oa[dt] = __builtin_amdgcn_mfma_f32_16x16x32_bf16(vfh, pfl, Oa[dt], 0, 0, 0);
                Oa[dt] = __builtin_amdgcn_mfma_f32_16x16x32_bf16(vfl, pfh, Oa[dt], 0, 0, 0);
            }
        }
    }
    const size_t base = (((size_t)b*32 + qt)*16 + ch)*64;
    float* op = Opart + (base + w*16 + c)*DDIM;
    #pragma unroll
    for (int dt = 0; dt < 8; dt++)
        *(f32x4*)(op + dt*16 + g*4) = Oa[dt];
    if (g == 0) {
        float* mlp = ml + (base + w*16 + c)*2;
        mlp[0] = mrun; mlp[1] = lrun;
    }
}

__global__ __launch_bounds__(256) void attn_reduce(const float* __restrict__ Opart,
        const float* __restrict__ ml, float* __restrict__ ao) {
    const int qt = blockIdx.x, b = blockIdx.y;
    const int tid = threadIdx.x;
    const int r = tid >> 2, qq = tid & 3;
    const int nch = (qt >> 1) + 1;
    const size_t base = ((size_t)b*32 + qt)*16;
    float M = -INFINITY;
    for (int i = 0; i < nch; i++) M = fmaxf(M, ml[(base+i)*128 + r*2]);
    float L = 0.f;
    for (int i = 0; i < nch; i++)
        L += ml[(base+i)*128 + r*2 + 1]*expf(ml[(base+i)*128 + r*2] - M);
    float o[32] = {};
    for (int i = 0; i < nch; i++) {
        float sc = expf(ml[(base+i)*128 + r*2] - M);
        const float* op = Opart + ((base+i)*64 + r)*DDIM + qq;
        #pragma unroll
        for (int m2 = 0; m2 < 32; m2++) o[m2] += sc*op[4*m2];
    }
    float linv = 1.0f / L;
    float* dst = ao + ((size_t)b*TSEQ + qt*64 + r)*DDIM + qq;
    #pragma unroll
    for (int m2 = 0; m2 < 32; m2++) dst[4*m2] = o[m2]*linv;
}

extern "C" void kernel_launch(void* const* d_in, const int* in_sizes, int n_in,
                              void* d_out, int out_size, void* d_ws, size_t ws_size,
                              hipStream_t stream) {
    const float* x     = (const float*)d_in[0];
    const int*   pos   = (const int*)d_in[1];
    const float* asim  = (const float*)d_in[2];
    const float* agate = (const float*)d_in[3];
    const float* qw    = (const float*)d_in[4];
    const float* kw    = (const float*)d_in[5];
    const float* vw    = (const float*)d_in[6];
    const float* ow    = (const float*)d_in[7];
    const float* msim  = (const float*)d_in[8];
    const float* mgate = (const float*)d_in[9];
    const float* w1    = (const float*)d_in[10];
    const float* w2    = (const float*)d_in[11];
    const int*   kqa   = (const int*)d_in[12];
    const int*   kqm   = (const int*)d_in[13];

    char* ws = (char*)d_ws;
    int*   counts_a = (int*)(ws + OFF_CA);
    int*   counts_m = (int*)(ws + OFF_CM);
    float* colinv   = (float*)(ws + OFF_CI);
    int*   poffs_a  = (int*)(ws + OFF_PA);
    int*   poffs_m  = (int*)(ws + OFF_PM);
    float* w_a      = (float*)(ws + OFF_WA);
    float* w_m      = (float*)(ws + OFF_WM);
    int*   list_a   = (int*)(ws + OFF_LA);
    int*   list_m   = (int*)(ws + OFF_LM);
    int*   rowtok_a = (int*)(ws + OFF_RTA);
    int*   rowtok_m = (int*)(ws + OFF_RTM);
    unsigned int* mb_a = (unsigned int*)(ws + OFF_MBA);
    unsigned int* mb_m = (unsigned int*)(ws + OFF_MBM);
    float* qb   = (float*)(ws + OFF_QB);
    float* kb   = (float*)(ws + OFF_KB);
    float* vb   = (float*)(ws + OFF_VB);
    float* ao   = (float*)(ws + OFF_AO);
    unsigned short* qhi = (unsigned short*)(ws + OFF_QHI);
    unsigned short* qlo = (unsigned short*)(ws + OFF_QLO);
    unsigned short* khi = (unsigned short*)(ws + OFF_KHI);
    unsigned short* klo = (unsigned short*)(ws + OFF_KLO);
    unsigned short* vTh = (unsigned short*)(ws + OFF_VTH);
    unsigned short* vTl = (unsigned short*)(ws + OFF_VTL);
    float* mlb  = (float*)(ws + OFF_ML);
    unsigned short* wqkvt = (unsigned short*)(ws + OFF_WQKVT);
    unsigned short* wot   = (unsigned short*)(ws + OFF_WOT);
    unsigned short* apop  = (unsigned short*)(ws + OFF_APOP);
    unsigned short* apqkv = (unsigned short*)(ws + OFF_APQKV);
    float* Opart = (float*)(ws + OFF_OP);
    unsigned short* apm   = (unsigned short*)(ws + OFF_APM);
    unsigned short* w1t   = (unsigned short*)(ws + OFF_W1T);
    unsigned short* ab2   = (unsigned short*)(ws + OFF_AB2);
    float* out = (float*)d_out;

    (void)hipMemsetAsync(ws + OFF_CA, 0, 512, stream);
    (void)hipMemsetAsync(ws + OFF_RTA, 0xFF, 64*1024, stream);
    (void)hipMemsetAsync(ws + OFF_QB, 0, MB(6), stream);

    colnorm_kernel<<<16, 256, 0, stream>>>(asim, msim, colinv);

    gating_kernel<<<NT, 256, 0, stream>>>(x, asim, agate, colinv, kqa, w_a, mb_a);
    list_build<<<NE, 256, 0, stream>>>(mb_a, counts_a, list_a);
    scan_pad<<<1, 64, 0, stream>>>(counts_a, poffs_a);
    rowmap_kernel<<<NE, 256, 0, stream>>>(counts_a, poffs_a, list_a, rowtok_a);
    pack_a<CDIM><<<dim3(16, ABCAP/64), 256, 0, stream>>>(x, rowtok_a, apqkv);
    pack_b<<<dim3(2, 16, NE), 256, 0, stream>>>(qw, wqkvt,                          CDIM, DDIM);
    pack_b<<<dim3(2, 16, NE), 256, 0, stream>>>(kw, wqkvt + (size_t)NE*CDIM*DDIM,   CDIM, DDIM);
    pack_b<<<dim3(2, 16, NE), 256, 0, stream>>>(vw, wqkvt + (size_t)2*NE*CDIM*DDIM, CDIM, DDIM);
    ggemm<GM_QKV, CDIM, DDIM><<<dim3(NTIL, 6), 256, 0, stream>>>(
        apqkv, wqkvt, w_a, counts_a, list_a, poffs_a, qb, kb, vb, nullptr);
    rope_cvt2<<<NT, 64, 0, stream>>>(qb, kb, pos, qhi, qlo, khi, klo);
    transpose_cvt2<<<dim3(2, 32, NB), 256, 0, stream>>>(vb, vTh, vTl, TSEQ, DDIM);
    attn_part<<<dim3(32, 16, NB), 256, 0, stream>>>(qhi, qlo, khi, klo, vTh, vTl, Opart, mlb);
    attn_reduce<<<dim3(32, NB), 256, 0, stream>>>(Opart, mlb, ao);

    pack_a<DDIM><<<dim3(2, ABCAP/64), 256, 0, stream>>>(ao, rowtok_a, apop);
    pack_b<<<dim3(16, 2, NE), 256, 0, stream>>>(ow, wot, DDIM, CDIM);
    (void)hipMemcpyAsync(out, x, (size_t)NT*CDIM*4, hipMemcpyDeviceToDevice, stream);
    ggemm<GM_OPROJ, DDIM, CDIM><<<dim3(NTIL, 8), 256, 0, stream>>>(
        apop, wot, w_a, counts_a, list_a, poffs_a, out, nullptr, nullptr, nullptr);

    gating_kernel<<<NT, 256, 0, stream>>>(out, msim, mgate, colinv + NE, kqm, w_m, mb_m);
    list_build<<<NE, 256, 0, stream>>>(mb_m, counts_m, list_m);
    scan_pad<<<1, 64, 0, stream>>>(counts_m, poffs_m);
    rowmap_kernel<<<NE, 256, 0, stream>>>(counts_m, poffs_m, list_m, rowtok_m);
    pack_a<CDIM><<<dim3(16, ABCAP/64), 256, 0, stream>>>(out, rowtok_m, apm);
    pack_b<<<dim3(32, 16, NE), 256, 0, stream>>>(w1, w1t, CDIM, FFDIM);
    ggemm<GM_MOE1, CDIM, FFDIM><<<dim3(NTIL, 16), 256, 0, stream>>>(
        apm, w1t, w_m, counts_m, list_m, poffs_m, nullptr, nullptr, nullptr, ab2);
    pack_b<<<dim3(16, 32, NE), 256, 0, stream>>>(w2, w1t, FFDIM, CDIM);
    ggemm<GM_MOE2, FFDIM, CDIM><<<dim3(NTIL, 16), 256, 0, stream>>>(
        ab2, w1t, w_m, counts_m, list_m, poffs_m, out, nullptr, nullptr, nullptr);
}